// Round 7
// baseline (199.126 us; speedup 1.0000x reference)
//
#include <hip/hip_runtime.h>
#include <math.h>

#define Bb 8
#define NTt 100
#define NPp 300
#define Cc 92
#define Aa 64

// ---------- shared math helpers (f32, op-for-op like the reference) ----------

__device__ __forceinline__ void iou_giou_f(const float* bt, const float* bp,
                                           float& iou, float& giou) {
  float ay1 = bt[0], ax1 = bt[1], ay2 = bt[2], ax2 = bt[3];
  float by1 = bp[0], bx1 = bp[1], by2 = bp[2], bx2 = bp[3];
  float area_a = fmaxf(ay2 - ay1, 0.0f) * fmaxf(ax2 - ax1, 0.0f);
  float area_b = fmaxf(by2 - by1, 0.0f) * fmaxf(bx2 - bx1, 0.0f);
  float inter = fmaxf(fminf(ay2, by2) - fmaxf(ay1, by1), 0.0f) *
                fmaxf(fminf(ax2, bx2) - fmaxf(ax1, bx1), 0.0f);
  float un = area_a + area_b - inter;
  iou = (un > 0.0f) ? (inter / un) : 0.0f;
  float enc = fmaxf(fmaxf(ay2, by2) - fminf(ay1, by1), 0.0f) *
              fmaxf(fmaxf(ax2, bx2) - fminf(ax1, bx1), 0.0f);
  giou = iou - ((enc > 0.0f) ? ((enc - un) / enc) : 0.0f);
}

__device__ __forceinline__ float box_cost_f(const float* bt, const float* bp,
                                            float& iou_out) {
  float iou, giou;
  iou_giou_f(bt, bp, iou, giou);
  iou_out = iou;
  float l1 = (fabsf(bt[0] - bp[0]) + fabsf(bt[1] - bp[1]) +
              fabsf(bt[2] - bp[2]) + fabsf(bt[3] - bp[3])) * 0.25f;
  return 2.0f * (1.0f - giou) + 5.0f * l1;
}

// ---------- DPP helper: wave64 f64 min (value only, fmin), result in lane 63 ----------

template <int CTRL>
__device__ __forceinline__ void dpp_fmin64(double& val) {
  union DU { double d; int i[2]; };
  DU a; a.d = val;
  int lo = __builtin_amdgcn_update_dpp(a.i[0], a.i[0], CTRL, 0xF, 0xF, false);
  int hi = __builtin_amdgcn_update_dpp(a.i[1], a.i[1], CTRL, 0xF, 0xF, false);
  DU o; o.i[0] = lo; o.i[1] = hi;
  val = fmin(val, o.d);
}

__device__ __forceinline__ double read_u_row(double u_lo, double u_hi, int i0u) {
  int ridx = i0u - 1;
  int src = ridx & 63;
  union DU { double d; int i[2]; };
  DU a, bb, r;
  a.d = u_lo; bb.d = u_hi;
  int lo0 = __builtin_amdgcn_readlane(a.i[0], src);
  int hi0 = __builtin_amdgcn_readlane(a.i[1], src);
  int lo1 = __builtin_amdgcn_readlane(bb.i[0], src);
  int hi1 = __builtin_amdgcn_readlane(bb.i[1], src);
  bool hih = (ridx >> 6) != 0;
  r.i[0] = hih ? lo1 : lo0;
  r.i[1] = hih ? hi1 : hi0;
  return r.d;
}

__device__ __forceinline__ int sel5(int s, int a0, int a1, int a2, int a3, int a4) {
  int r = a4;
  r = (s == 3) ? a3 : r;
  r = (s == 2) ? a2 : r;
  r = (s == 1) ? a1 : r;
  r = (s == 0) ? a0 : r;
  return r;
}

// ---------- fused kernel ----------
// 8 blocks x 256 threads. Phase 1 (cls+cost) uses all 4 waves; vanilla JV
// (exact reference trajectory, zero-init duals) + partial reductions run on
// wave 0 only, barrier-free, all per-column state in registers.
// Column mapping: lane L (<60) owns cols j = 5L+1 .. 5L+5 (lane-contiguous =>
// ctz-of-ballot = smallest j, matching np.argmin's first-min tie rule).
// Poison-sentinel scheme: when a column settles, its mv -> -INF (freezes way,
// keeps mv at -INF through fmin/sub) and its msk -> +INF (so the candidate
// cand = fmax(mv, msk) = +INF is excluded). Scan and minv updates run with NO
// used-gating; live slots see bit-identical FP sequences to the reference.

template <bool STAGE>
__global__ void __launch_bounds__(256) fused_kernel(
    const float* __restrict__ category, const float* __restrict__ attribute,
    const float* __restrict__ bbox, const int* __restrict__ num_objects,
    const float* __restrict__ cat_preds, const float* __restrict__ attribute_preds,
    const float* __restrict__ box_preds, float* __restrict__ gcost,
    double* __restrict__ partials, float* __restrict__ diag) {
  extern __shared__ char smem[];
  const int b = blockIdx.x;
  const int tid = threadIdx.x;
  const int lane = tid & 63;
  const int wid = tid >> 6;

  float* lds_cost = (float*)smem;
  int* cls_l = (int*)(smem + (STAGE ? NTt * NPp * 4 : 0));   // 104 ints

  const int n = num_objects[b];

  // ---- phase 1: cls + cost rows (all 4 waves) ----
  float* costb = STAGE ? lds_cost : (gcost + (size_t)b * NTt * NPp);
  const float4* bp4 = (const float4*)(box_preds + (size_t)b * NPp * 4);

  for (int t = wid; t < n; t += 4) {
    int bt = b * NTt + t;
    const float* crow = category + (size_t)bt * Cc;
    float cc0 = (lane < Cc) ? crow[lane] : 0.0f;
    float cc1 = (lane + 64 < Cc) ? crow[lane + 64] : 0.0f;
    unsigned long long m0 = __ballot(cc0 == 1.0f);
    unsigned long long m1 = __ballot(cc1 == 1.0f);
    int cl = m0 ? __builtin_ctzll(m0) : (m1 ? 64 + __builtin_ctzll(m1) : 0);
    if (lane == 0) cls_l[t] = cl;

    float tb[4] = {bbox[bt * 4 + 0], bbox[bt * 4 + 1],
                   bbox[bt * 4 + 2], bbox[bt * 4 + 3]};
    const float* cp = cat_preds + (size_t)b * NPp * Cc + cl;
    for (int p = lane; p < NPp; p += 64) {
      float4 bv = bp4[p];
      float pb[4] = {bv.x, bv.y, bv.z, bv.w};
      float iou;
      float bc = box_cost_f(tb, pb, iou);
      float pc = cp[(size_t)p * Cc];
      costb[t * NPp + p] = (1.0f - pc) + bc;
    }
  }
  __syncthreads();

  if (tid >= 64) return;   // waves 1-3 done; wave 0 continues barrier-free

  // ---- phase 2: vanilla JV (exact reference trajectory) ----
  const double INF = __builtin_inf();
  const bool active = lane < 60;
  const int laneOff = active ? 5 * lane : 0;   // clamp inactive lanes to row start

  double v0 = 0.0, v1 = 0.0, v2 = 0.0, v3 = 0.0, v4 = 0.0;
  double u_lo = 0.0, u_hi = 0.0;                 // u[lane+1], u[lane+65]
  int wp0 = 0, wp1 = 0, wp2 = 0, wp3 = 0, wp4 = 0;   // (way<<7)|pj per slot
  int itg = 0;                                    // diagnostic iteration counter

  for (int i = 1; i <= n; ++i) {
    double mv0 = INF, mv1 = INF, mv2 = INF, mv3 = INF, mv4 = INF;
    const double mk_init = active ? -INF : INF;
    double mk0 = mk_init, mk1 = mk_init, mk2 = mk_init, mk3 = mk_init, mk4 = mk_init;
    int usedmask = 0, uf = 0;
    int j0u = 0, i0u = i;

    while (true) {
      // add row i0 to the path-row set
      { int ridx = i0u - 1; if ((ridx & 63) == lane) uf |= 1 << (ridx >> 6); }

      const float* rowp = costb + (i0u - 1) * NPp + laneOff;
      float ca = rowp[0], cb2 = rowp[1], cc = rowp[2], cd = rowp[3], ce = rowp[4];
      double ui0 = read_u_row(u_lo, u_hi, i0u);   // VALU, overlaps LDS wait

      // ungated scan: for settled slots mv=-INF => no way update, mv stays -INF
      {
        double cur = (double)ca - ui0 - v0;
        wp0 = (cur < mv0) ? ((j0u << 7) | (wp0 & 127)) : wp0;
        mv0 = fmin(mv0, cur);
      }
      {
        double cur = (double)cb2 - ui0 - v1;
        wp1 = (cur < mv1) ? ((j0u << 7) | (wp1 & 127)) : wp1;
        mv1 = fmin(mv1, cur);
      }
      {
        double cur = (double)cc - ui0 - v2;
        wp2 = (cur < mv2) ? ((j0u << 7) | (wp2 & 127)) : wp2;
        mv2 = fmin(mv2, cur);
      }
      {
        double cur = (double)cd - ui0 - v3;
        wp3 = (cur < mv3) ? ((j0u << 7) | (wp3 & 127)) : wp3;
        mv3 = fmin(mv3, cur);
      }
      {
        double cur = (double)ce - ui0 - v4;
        wp4 = (cur < mv4) ? ((j0u << 7) | (wp4 & 127)) : wp4;
        mv4 = fmin(mv4, cur);
      }

      // candidates: settled/inactive slots become +INF via the mask
      double cv0 = fmax(mv0, mk0);
      double cv1 = fmax(mv1, mk1);
      double cv2 = fmax(mv2, mk2);
      double cv3 = fmax(mv3, mk3);
      double cv4 = fmax(mv4, mk4);

      // local min (value-only fmin tree)
      double m01 = fmin(fmin(fmin(cv0, cv1), fmin(cv2, cv3)), cv4);

      // local argmin slot (first-min ascending k) + pack
      int k0 = (cv3 == m01) ? 3 : 4;
      k0 = (cv2 == m01) ? 2 : k0;
      k0 = (cv1 == m01) ? 1 : k0;
      k0 = (cv0 == m01) ? 0 : k0;
      int ploc = sel5(k0, wp0 & 127, wp1 & 127, wp2 & 127, wp3 & 127, wp4 & 127);
      int p01 = ((laneOff + k0 + 1) << 7) | ploc;

      // wave64 f64 min via DPP fmin -> lane 63
      double mvred = m01;
      dpp_fmin64<0x111>(mvred);   // row_shr:1
      dpp_fmin64<0x112>(mvred);   // row_shr:2
      dpp_fmin64<0x114>(mvred);   // row_shr:4
      dpp_fmin64<0x118>(mvred);   // row_shr:8
      dpp_fmin64<0x142>(mvred);   // row_bcast:15
      dpp_fmin64<0x143>(mvred);   // row_bcast:31
      union DU { double d; int i[2]; };
      DU w; w.d = mvred;
      DU r;
      r.i[0] = __builtin_amdgcn_readlane(w.i[0], 63);
      r.i[1] = __builtin_amdgcn_readlane(w.i[1], 63);
      double delta = r.d;

      // winner: smallest lane holding the min == smallest j
      unsigned long long hit = __ballot(m01 == delta);
      int winlane = __builtin_ctzll(hit);
      int wpk = __builtin_amdgcn_readlane(p01, winlane);
      int j1u = wpk >> 7, i1u = wpk & 127;

      // dual updates (exact reference order), then settle the winner column
      if (uf & 1) u_lo += delta;
      if (uf & 2) u_hi += delta;
      v0 -= (usedmask & 1)  ? delta : 0.0;
      v1 -= (usedmask & 2)  ? delta : 0.0;
      v2 -= (usedmask & 4)  ? delta : 0.0;
      v3 -= (usedmask & 8)  ? delta : 0.0;
      v4 -= (usedmask & 16) ? delta : 0.0;
      mv0 -= delta; mv1 -= delta; mv2 -= delta; mv3 -= delta; mv4 -= delta;

      // settle column j1 (poison its slot)
      int jm = j1u - 1;
      int wl = jm / 5;
      int sk = jm - 5 * wl;
      if (lane == wl) {
        usedmask |= 1 << sk;
        if      (sk == 0) { mv0 = -INF; mk0 = INF; }
        else if (sk == 1) { mv1 = -INF; mk1 = INF; }
        else if (sk == 2) { mv2 = -INF; mk2 = INF; }
        else if (sk == 3) { mv3 = -INF; mk3 = INF; }
        else              { mv4 = -INF; mk4 = INF; }
      }

      // diagnostic: one distinct 64B line per inner iteration (capped 1024/batch)
      if (diag != nullptr && lane == 0 && itg < 1024)
        __builtin_nontemporal_store(1.0f, diag + ((b << 14) + (itg << 4)));
      ++itg;

      j0u = j1u; i0u = i1u;
      if (i0u == 0) break;
    }

    // ---- augment alternating path (register walk, all lanes, uniform) ----
    {
      int jj = j0u;
      int idx = jj - 1;
      int owner = idx / 5;
      int slot = idx - 5 * owner;
      int f0 = __shfl(wp0, owner), f1 = __shfl(wp1, owner),
          f2 = __shfl(wp2, owner), f3 = __shfl(wp3, owner),
          f4 = __shfl(wp4, owner);
      int wpv = sel5(slot, f0, f1, f2, f3, f4);
      int wayv = wpv >> 7;

      while (true) {
        int jp = wayv;                        // uniform
        int newv;
        int wayn = 0;
        if (jp != 0) {
          int idx2 = jp - 1;
          int owner2 = idx2 / 5;
          int slot2 = idx2 - 5 * owner2;
          int g0 = __shfl(wp0, owner2), g1 = __shfl(wp1, owner2),
              g2 = __shfl(wp2, owner2), g3 = __shfl(wp3, owner2),
              g4 = __shfl(wp4, owner2);
          int wpn = sel5(slot2, g0, g1, g2, g3, g4);
          wayn = wpn >> 7;
          newv = wpn & 127;                   // old pj[jp]
        } else {
          newv = i;
        }
        if (lane == owner) {
          if      (slot == 0) wp0 = (wp0 & ~127) | newv;
          else if (slot == 1) wp1 = (wp1 & ~127) | newv;
          else if (slot == 2) wp2 = (wp2 & ~127) | newv;
          else if (slot == 3) wp3 = (wp3 & ~127) | newv;
          else                wp4 = (wp4 & ~127) | newv;
        }
        if (jp == 0) break;
        jj = jp;
        idx = jj - 1;
        owner = idx / 5;
        slot = idx - 5 * owner;
        wayv = wayn;
      }
    }
  }

  // ---- phase 3: per-batch partial reductions (each lane: its own 5 cols) ----
  double acc[7];
  #pragma unroll
  for (int q = 0; q < 7; ++q) acc[q] = 0.0;
  // 0 cat, 1 attr, 2 box, 3 iou, 4 exist, 5 cnt50, 6 cntall

  const float EPSF = 1e-7f;
  const float HIF  = (float)(1.0 - 1e-7);

  if (active) {
    #pragma unroll
    for (int k = 0; k < 5; ++k) {
      int prowv = (k == 0 ? wp0 : k == 1 ? wp1 : k == 2 ? wp2 : k == 3 ? wp3 : wp4) & 127;
      if (prowv != 0) {
        int j = 5 * lane + k;                 // 0-based column
        int t = prowv - 1;
        int bt = b * NTt + t;
        int idx = b * NPp + j;

        float pc = cat_preds[(size_t)idx * Cc + cls_l[t]];
        acc[0] += (double)(-logf(pc + 1e-5f));

        const float* yrow = attribute + (size_t)bt * Aa;
        const float* prw  = attribute_preds + (size_t)idx * Aa;
        float af = 0.0f;
        for (int a = 0; a < Aa; ++a) {
          float y = yrow[a];
          float p = fminf(fmaxf(prw[a], EPSF), HIF);
          float cev = -(y * logf(p) + (1.0f - y) * logf(1.0f - p));
          float pt = y * p + (1.0f - y) * (1.0f - p);
          float alpha = y * 0.25f + (1.0f - y) * 0.75f;
          float om = 1.0f - pt;
          af += alpha * (om * om) * cev;
        }
        acc[1] += (double)af;

        const float* btp = bbox + (size_t)bt * 4;
        const float* bpp = box_preds + (size_t)idx * 4;
        float iou;
        float bc = box_cost_f(btp, bpp, iou);
        acc[2] += (double)bc;
        float ia = 1.0f - iou;
        acc[3] += (double)ia;
        if (ia >= 0.5f) acc[5] += 1.0;
        for (int rr = 50; rr < 100; rr += 5) {
          float thr = (float)((double)rr / 100.0);
          if (ia >= thr) acc[6] += 1.0;
        }

        float yp = 1.0f - cat_preds[(size_t)idx * Cc + 0];
        float pn = yp / yp;
        pn = fminf(fmaxf(pn, EPSF), HIF);
        acc[4] += (double)(-logf(pn));
      }
    }
  }

  #pragma unroll
  for (int q = 0; q < 7; ++q) {
    #pragma unroll
    for (int off = 32; off >= 1; off >>= 1) acc[q] += __shfl_xor(acc[q], off);
  }

  // num_predicted contribution: count cat_preds[b,1,:] < 0.5
  const float* cpb1 = cat_preds + ((size_t)b * NPp + 1) * Cc;
  float q0 = (lane < Cc) ? cpb1[lane] : 1.0f;
  float q1 = (lane + 64 < Cc) ? cpb1[lane + 64] : 1.0f;
  unsigned long long mm0 = __ballot(q0 < 0.5f);
  unsigned long long mm1 = __ballot(q1 < 0.5f);
  double npredd = (double)(__popcll(mm0) + __popcll(mm1));

  if (lane == 0) {
    #pragma unroll
    for (int q = 0; q < 7; ++q) partials[b * 8 + q] = acc[q];
    partials[b * 8 + 7] = npredd;
  }
}

// ---------- combine kernel: fixed-order sum of 8 batches -> 8 outputs ----------

__global__ void combine_kernel(const double* __restrict__ partials,
                               const int* __restrict__ num_objects,
                               float* __restrict__ out) {
  if (threadIdx.x != 0) return;
  double t[8];
  #pragma unroll
  for (int q = 0; q < 8; ++q) t[q] = 0.0;
  for (int b = 0; b < Bb; ++b)
    for (int q = 0; q < 8; ++q) t[q] += partials[b * 8 + q];

  int s = 0;
  for (int b = 0; b < Bb; ++b) s += num_objects[b];
  float tno = (float)s;

  float category_cost  = (float)t[0] / tno;
  float attribute_cost = (float)t[1] / tno;
  float box_cost       = (float)t[2] / tno;
  float exist_loss     = (float)t[4] / (float)(Bb * NPp);
  float total = category_cost + attribute_cost + box_cost + exist_loss;
  float iou_metric = (float)t[3] / tno;
  float npredf = (float)t[7];
  float mAP50 = (float)t[5] / npredf;
  float m5095 = (float)t[6] / (npredf * 10.0f);

  out[0] = total;
  out[1] = category_cost;
  out[2] = attribute_cost;
  out[3] = box_cost;
  out[4] = exist_loss;
  out[5] = iou_metric;
  out[6] = mAP50;
  out[7] = m5095;
}

// ---------- launcher ----------

extern "C" void kernel_launch(void* const* d_in, const int* in_sizes, int n_in,
                              void* d_out, int out_size, void* d_ws, size_t ws_size,
                              hipStream_t stream) {
  const float* category        = (const float*)d_in[0];
  const float* attribute       = (const float*)d_in[1];
  const float* bbox            = (const float*)d_in[2];
  const int*   num_objects     = (const int*)d_in[3];
  const float* cat_preds       = (const float*)d_in[4];
  const float* attribute_preds = (const float*)d_in[5];
  const float* box_preds       = (const float*)d_in[6];
  float* out = (float*)d_out;

  double* partials = (double*)d_ws;                       // 8*8 doubles = 512 B
  float*  gcost    = (float*)((char*)d_ws + 4096);        // 960000 B (fallback only)

  const int STAGED_LDS = NTt * NPp * 4 + 104 * 4;         // 120416
  const int SMALL_LDS  = 104 * 4;

  hipError_t e = hipFuncSetAttribute(
      reinterpret_cast<const void*>(&fused_kernel<true>),
      hipFuncAttributeMaxDynamicSharedMemorySize, STAGED_LDS);
  if (e == hipSuccess) {
    // diagnostic region: 8 batches x 64KB of 64B lines, at ws+4096
    float* diag = (ws_size >= (size_t)(4096 + 8 * 65536))
                      ? (float*)((char*)d_ws + 4096) : nullptr;
    fused_kernel<true><<<Bb, 256, STAGED_LDS, stream>>>(
        category, attribute, bbox, num_objects, cat_preds, attribute_preds,
        box_preds, gcost, partials, diag);
  } else {
    fused_kernel<false><<<Bb, 256, SMALL_LDS, stream>>>(
        category, attribute, bbox, num_objects, cat_preds, attribute_preds,
        box_preds, gcost, partials, (float*)nullptr);
  }

  combine_kernel<<<1, 64, 0, stream>>>(partials, num_objects, out);
}

// Round 8
// 189.647 us; speedup vs baseline: 1.0500x; 1.0500x over previous
//
#include <hip/hip_runtime.h>
#include <math.h>

#define Bb 8
#define NTt 100
#define NPp 300
#define Cc 92
#define Aa 64

// ---------- shared math helpers (f32, op-for-op like the reference) ----------

__device__ __forceinline__ void iou_giou_f(const float* bt, const float* bp,
                                           float& iou, float& giou) {
  float ay1 = bt[0], ax1 = bt[1], ay2 = bt[2], ax2 = bt[3];
  float by1 = bp[0], bx1 = bp[1], by2 = bp[2], bx2 = bp[3];
  float area_a = fmaxf(ay2 - ay1, 0.0f) * fmaxf(ax2 - ax1, 0.0f);
  float area_b = fmaxf(by2 - by1, 0.0f) * fmaxf(bx2 - bx1, 0.0f);
  float inter = fmaxf(fminf(ay2, by2) - fmaxf(ay1, by1), 0.0f) *
                fmaxf(fminf(ax2, bx2) - fmaxf(ax1, bx1), 0.0f);
  float un = area_a + area_b - inter;
  iou = (un > 0.0f) ? (inter / un) : 0.0f;
  float enc = fmaxf(fmaxf(ay2, by2) - fminf(ay1, by1), 0.0f) *
              fmaxf(fmaxf(ax2, bx2) - fminf(ax1, bx1), 0.0f);
  giou = iou - ((enc > 0.0f) ? ((enc - un) / enc) : 0.0f);
}

__device__ __forceinline__ float box_cost_f(const float* bt, const float* bp,
                                            float& iou_out) {
  float iou, giou;
  iou_giou_f(bt, bp, iou, giou);
  iou_out = iou;
  float l1 = (fabsf(bt[0] - bp[0]) + fabsf(bt[1] - bp[1]) +
              fabsf(bt[2] - bp[2]) + fabsf(bt[3] - bp[3])) * 0.25f;
  return 2.0f * (1.0f - giou) + 5.0f * l1;
}

// ---------- DPP helper: wave64 f64 min (value only, fmin), result in lane 63 ----------

template <int CTRL>
__device__ __forceinline__ void dpp_fmin64(double& val) {
  union DU { double d; int i[2]; };
  DU a; a.d = val;
  int lo = __builtin_amdgcn_update_dpp(a.i[0], a.i[0], CTRL, 0xF, 0xF, false);
  int hi = __builtin_amdgcn_update_dpp(a.i[1], a.i[1], CTRL, 0xF, 0xF, false);
  DU o; o.i[0] = lo; o.i[1] = hi;
  val = fmin(val, o.d);
}

__device__ __forceinline__ double read_u_row(double u_lo, double u_hi, int i0u) {
  int ridx = i0u - 1;
  int src = ridx & 63;
  union DU { double d; int i[2]; };
  DU a, bb, r;
  a.d = u_lo; bb.d = u_hi;
  int lo0 = __builtin_amdgcn_readlane(a.i[0], src);
  int hi0 = __builtin_amdgcn_readlane(a.i[1], src);
  int lo1 = __builtin_amdgcn_readlane(bb.i[0], src);
  int hi1 = __builtin_amdgcn_readlane(bb.i[1], src);
  bool hih = (ridx >> 6) != 0;
  r.i[0] = hih ? lo1 : lo0;
  r.i[1] = hih ? hi1 : hi0;
  return r.d;
}

__device__ __forceinline__ int sel5(int s, int a0, int a1, int a2, int a3, int a4) {
  int r = a4;
  r = (s == 3) ? a3 : r;
  r = (s == 2) ? a2 : r;
  r = (s == 1) ? a1 : r;
  r = (s == 0) ? a0 : r;
  return r;
}

// ---------- fused kernel ----------
// 8 blocks x 256 threads, __launch_bounds__(256, 1): min-occupancy hint so the
// allocator keeps the whole JV state in VGPRs (spill hypothesis from R7).
// Phase 1 (cls+cost) uses all 4 waves; vanilla JV (exact reference trajectory)
// + partial reductions run on wave 0 only, barrier-free, state in registers.
// Column mapping: lane L (<60) owns cols j = 5L+1 .. 5L+5 (lane-contiguous =>
// ctz-of-ballot = smallest j, matching np.argmin's first-min tie rule).
// Poison scan: settled column's mv = -INF freezes its way and survives
// fmin/sub ungated; candidate masking still via usedmask selects.

template <bool STAGE>
__global__ void __launch_bounds__(256, 1) fused_kernel(
    const float* __restrict__ category, const float* __restrict__ attribute,
    const float* __restrict__ bbox, const int* __restrict__ num_objects,
    const float* __restrict__ cat_preds, const float* __restrict__ attribute_preds,
    const float* __restrict__ box_preds, float* __restrict__ gcost,
    double* __restrict__ partials, float* __restrict__ diag) {
  extern __shared__ char smem[];
  const int b = blockIdx.x;
  const int tid = threadIdx.x;
  const int lane = tid & 63;
  const int wid = tid >> 6;

  float* lds_cost = (float*)smem;
  int* cls_l = (int*)(smem + (STAGE ? NTt * NPp * 4 : 0));   // 104 ints

  const int n = num_objects[b];

  // ---- phase 1: cls + cost rows (all 4 waves) ----
  float* costb = STAGE ? lds_cost : (gcost + (size_t)b * NTt * NPp);
  const float4* bp4 = (const float4*)(box_preds + (size_t)b * NPp * 4);

  for (int t = wid; t < n; t += 4) {
    int bt = b * NTt + t;
    const float* crow = category + (size_t)bt * Cc;
    float cc0 = (lane < Cc) ? crow[lane] : 0.0f;
    float cc1 = (lane + 64 < Cc) ? crow[lane + 64] : 0.0f;
    unsigned long long m0 = __ballot(cc0 == 1.0f);
    unsigned long long m1 = __ballot(cc1 == 1.0f);
    int cl = m0 ? __builtin_ctzll(m0) : (m1 ? 64 + __builtin_ctzll(m1) : 0);
    if (lane == 0) cls_l[t] = cl;

    float tb[4] = {bbox[bt * 4 + 0], bbox[bt * 4 + 1],
                   bbox[bt * 4 + 2], bbox[bt * 4 + 3]};
    const float* cp = cat_preds + (size_t)b * NPp * Cc + cl;
    for (int p = lane; p < NPp; p += 64) {
      float4 bv = bp4[p];
      float pb[4] = {bv.x, bv.y, bv.z, bv.w};
      float iou;
      float bc = box_cost_f(tb, pb, iou);
      float pc = cp[(size_t)p * Cc];
      costb[t * NPp + p] = (1.0f - pc) + bc;
    }
  }
  __syncthreads();

  if (tid >= 64) return;   // waves 1-3 done; wave 0 continues barrier-free

  long long t_jv0 = clock64();

  // ---- phase 2: vanilla JV (exact reference trajectory) ----
  const double INF = __builtin_inf();
  const bool active = lane < 60;
  const int laneOff = active ? 5 * lane : 0;   // clamp inactive lanes

  double v0 = 0.0, v1 = 0.0, v2 = 0.0, v3 = 0.0, v4 = 0.0;
  double u_lo = 0.0, u_hi = 0.0;                 // u[lane+1], u[lane+65]
  int wp0 = 0, wp1 = 0, wp2 = 0, wp3 = 0, wp4 = 0;   // (way<<7)|pj per slot

  for (int i = 1; i <= n; ++i) {
    double mv0 = INF, mv1 = INF, mv2 = INF, mv3 = INF, mv4 = INF;
    int usedmask = 0, uf = 0;
    int j0u = 0, i0u = i;

    while (true) {
      // add row i0 to the path-row set
      { int ridx = i0u - 1; if ((ridx & 63) == lane) uf |= 1 << (ridx >> 6); }

      const float* rowp = costb + (i0u - 1) * NPp + laneOff;
      float ca = rowp[0], cb2 = rowp[1], cc = rowp[2], cd = rowp[3], ce = rowp[4];
      double ui0 = read_u_row(u_lo, u_hi, i0u);   // VALU, overlaps LDS wait

      // ungated scan: settled slots (mv=-INF) never update way, stay -INF
      {
        double cur = (double)ca - ui0 - v0;
        wp0 = (cur < mv0) ? ((j0u << 7) | (wp0 & 127)) : wp0;
        mv0 = fmin(mv0, cur);
      }
      {
        double cur = (double)cb2 - ui0 - v1;
        wp1 = (cur < mv1) ? ((j0u << 7) | (wp1 & 127)) : wp1;
        mv1 = fmin(mv1, cur);
      }
      {
        double cur = (double)cc - ui0 - v2;
        wp2 = (cur < mv2) ? ((j0u << 7) | (wp2 & 127)) : wp2;
        mv2 = fmin(mv2, cur);
      }
      {
        double cur = (double)cd - ui0 - v3;
        wp3 = (cur < mv3) ? ((j0u << 7) | (wp3 & 127)) : wp3;
        mv3 = fmin(mv3, cur);
      }
      {
        double cur = (double)ce - ui0 - v4;
        wp4 = (cur < mv4) ? ((j0u << 7) | (wp4 & 127)) : wp4;
        mv4 = fmin(mv4, cur);
      }

      // candidates: settled/inactive slots -> INF via select
      double cv0 = (!active || (usedmask & 1))  ? INF : mv0;
      double cv1 = (!active || (usedmask & 2))  ? INF : mv1;
      double cv2 = (!active || (usedmask & 4))  ? INF : mv2;
      double cv3 = (!active || (usedmask & 8))  ? INF : mv3;
      double cv4 = (!active || (usedmask & 16)) ? INF : mv4;

      // local min (value-only fmin tree)
      double m01 = fmin(fmin(fmin(cv0, cv1), fmin(cv2, cv3)), cv4);

      // local argmin slot (first-min ascending k) + pack
      int k0 = (cv3 == m01) ? 3 : 4;
      k0 = (cv2 == m01) ? 2 : k0;
      k0 = (cv1 == m01) ? 1 : k0;
      k0 = (cv0 == m01) ? 0 : k0;
      int ploc = sel5(k0, wp0 & 127, wp1 & 127, wp2 & 127, wp3 & 127, wp4 & 127);
      int p01 = ((laneOff + k0 + 1) << 7) | ploc;

      // wave64 f64 min via DPP fmin -> lane 63
      double mvred = m01;
      dpp_fmin64<0x111>(mvred);   // row_shr:1
      dpp_fmin64<0x112>(mvred);   // row_shr:2
      dpp_fmin64<0x114>(mvred);   // row_shr:4
      dpp_fmin64<0x118>(mvred);   // row_shr:8
      dpp_fmin64<0x142>(mvred);   // row_bcast:15
      dpp_fmin64<0x143>(mvred);   // row_bcast:31
      union DU { double d; int i[2]; };
      DU w; w.d = mvred;
      DU r;
      r.i[0] = __builtin_amdgcn_readlane(w.i[0], 63);
      r.i[1] = __builtin_amdgcn_readlane(w.i[1], 63);
      double delta = r.d;

      // winner: smallest lane holding the min == smallest j
      unsigned long long hit = __ballot(m01 == delta);
      int winlane = __builtin_ctzll(hit);
      int wpk = __builtin_amdgcn_readlane(p01, winlane);
      int j1u = wpk >> 7, i1u = wpk & 127;

      // dual updates (exact reference order), then settle the winner column
      if (uf & 1) u_lo += delta;
      if (uf & 2) u_hi += delta;
      v0 -= (usedmask & 1)  ? delta : 0.0;
      v1 -= (usedmask & 2)  ? delta : 0.0;
      v2 -= (usedmask & 4)  ? delta : 0.0;
      v3 -= (usedmask & 8)  ? delta : 0.0;
      v4 -= (usedmask & 16) ? delta : 0.0;
      mv0 -= delta; mv1 -= delta; mv2 -= delta; mv3 -= delta; mv4 -= delta;

      // settle column j1 (poison its slot)
      int jm = j1u - 1;
      int wl = jm / 5;
      int sk = jm - 5 * wl;
      if (lane == wl) {
        usedmask |= 1 << sk;
        if      (sk == 0) mv0 = -INF;
        else if (sk == 1) mv1 = -INF;
        else if (sk == 2) mv2 = -INF;
        else if (sk == 3) mv3 = -INF;
        else              mv4 = -INF;
      }

      j0u = j1u; i0u = i1u;
      if (i0u == 0) break;
    }

    // ---- augment alternating path (uniform readlane walk) ----
    {
      int jj = j0u;
      int idx = jj - 1;
      int owner = idx / 5;
      int slot = idx - 5 * owner;
      int f0 = __builtin_amdgcn_readlane(wp0, owner),
          f1 = __builtin_amdgcn_readlane(wp1, owner),
          f2 = __builtin_amdgcn_readlane(wp2, owner),
          f3 = __builtin_amdgcn_readlane(wp3, owner),
          f4 = __builtin_amdgcn_readlane(wp4, owner);
      int wpv = sel5(slot, f0, f1, f2, f3, f4);
      int wayv = wpv >> 7;

      while (true) {
        int jp = wayv;                        // uniform
        int newv;
        int wayn = 0;
        if (jp != 0) {
          int idx2 = jp - 1;
          int owner2 = idx2 / 5;
          int slot2 = idx2 - 5 * owner2;
          int g0 = __builtin_amdgcn_readlane(wp0, owner2),
              g1 = __builtin_amdgcn_readlane(wp1, owner2),
              g2 = __builtin_amdgcn_readlane(wp2, owner2),
              g3 = __builtin_amdgcn_readlane(wp3, owner2),
              g4 = __builtin_amdgcn_readlane(wp4, owner2);
          int wpn = sel5(slot2, g0, g1, g2, g3, g4);
          wayn = wpn >> 7;
          newv = wpn & 127;                   // old pj[jp]
        } else {
          newv = i;
        }
        if (lane == owner) {
          if      (slot == 0) wp0 = (wp0 & ~127) | newv;
          else if (slot == 1) wp1 = (wp1 & ~127) | newv;
          else if (slot == 2) wp2 = (wp2 & ~127) | newv;
          else if (slot == 3) wp3 = (wp3 & ~127) | newv;
          else                wp4 = (wp4 & ~127) | newv;
        }
        if (jp == 0) break;
        jj = jp;
        idx = jj - 1;
        owner = idx / 5;
        slot = idx - 5 * owner;
        wayv = wayn;
      }
    }
  }

  long long t_jv1 = clock64();

  // ---- phase 3: per-batch partial reductions (each lane: its own 5 cols) ----
  double acc[7];
  #pragma unroll
  for (int q = 0; q < 7; ++q) acc[q] = 0.0;
  // 0 cat, 1 attr, 2 box, 3 iou, 4 exist, 5 cnt50, 6 cntall

  const float EPSF = 1e-7f;
  const float HIF  = (float)(1.0 - 1e-7);

  if (active) {
    #pragma unroll
    for (int k = 0; k < 5; ++k) {
      int prowv = (k == 0 ? wp0 : k == 1 ? wp1 : k == 2 ? wp2 : k == 3 ? wp3 : wp4) & 127;
      if (prowv != 0) {
        int j = 5 * lane + k;                 // 0-based column
        int t = prowv - 1;
        int bt = b * NTt + t;
        int idx = b * NPp + j;

        float pc = cat_preds[(size_t)idx * Cc + cls_l[t]];
        acc[0] += (double)(-logf(pc + 1e-5f));

        const float4* yrow4 = (const float4*)(attribute + (size_t)bt * Aa);
        const float4* prw4  = (const float4*)(attribute_preds + (size_t)idx * Aa);
        float af = 0.0f;
        #pragma unroll 4
        for (int a4 = 0; a4 < Aa / 4; ++a4) {
          float4 yv = yrow4[a4];
          float4 pv = prw4[a4];
          float ys[4] = {yv.x, yv.y, yv.z, yv.w};
          float ps[4] = {pv.x, pv.y, pv.z, pv.w};
          #pragma unroll
          for (int e = 0; e < 4; ++e) {
            float y = ys[e];
            float p = fminf(fmaxf(ps[e], EPSF), HIF);
            float cev = -(y * logf(p) + (1.0f - y) * logf(1.0f - p));
            float pt = y * p + (1.0f - y) * (1.0f - p);
            float alpha = y * 0.25f + (1.0f - y) * 0.75f;
            float om = 1.0f - pt;
            af += alpha * (om * om) * cev;
          }
        }
        acc[1] += (double)af;

        const float* btp = bbox + (size_t)bt * 4;
        const float* bpp = box_preds + (size_t)idx * 4;
        float iou;
        float bc = box_cost_f(btp, bpp, iou);
        acc[2] += (double)bc;
        float ia = 1.0f - iou;
        acc[3] += (double)ia;
        if (ia >= 0.5f) acc[5] += 1.0;
        for (int rr = 50; rr < 100; rr += 5) {
          float thr = (float)((double)rr / 100.0);
          if (ia >= thr) acc[6] += 1.0;
        }

        float yp = 1.0f - cat_preds[(size_t)idx * Cc + 0];
        float pn = yp / yp;
        pn = fminf(fmaxf(pn, EPSF), HIF);
        acc[4] += (double)(-logf(pn));
      }
    }
  }

  #pragma unroll
  for (int q = 0; q < 7; ++q) {
    #pragma unroll
    for (int off = 32; off >= 1; off >>= 1) acc[q] += __shfl_xor(acc[q], off);
  }

  // num_predicted contribution: count cat_preds[b,1,:] < 0.5
  const float* cpb1 = cat_preds + ((size_t)b * NPp + 1) * Cc;
  float q0 = (lane < Cc) ? cpb1[lane] : 1.0f;
  float q1 = (lane + 64 < Cc) ? cpb1[lane + 64] : 1.0f;
  unsigned long long mm0 = __ballot(q0 < 0.5f);
  unsigned long long mm1 = __ballot(q1 < 0.5f);
  double npredd = (double)(__popcll(mm0) + __popcll(mm1));

  if (lane == 0) {
    #pragma unroll
    for (int q = 0; q < 7; ++q) partials[b * 8 + q] = acc[q];
    partials[b * 8 + 7] = npredd;

    // diagnostic: encode JV-phase cycles into WRITE_SIZE.
    // lines written = jv_cycles >> 12 (4096-cy units), one 64B line each.
    if (diag != nullptr) {
      int nl = (int)((t_jv1 - t_jv0) >> 12);
      if (nl > 1024) nl = 1024;
      for (int w2 = 0; w2 < nl; ++w2)
        __builtin_nontemporal_store(1.0f, diag + ((b << 14) + (w2 << 4)));
    }
  }
}

// ---------- combine kernel: fixed-order sum of 8 batches -> 8 outputs ----------

__global__ void combine_kernel(const double* __restrict__ partials,
                               const int* __restrict__ num_objects,
                               float* __restrict__ out) {
  if (threadIdx.x != 0) return;
  double t[8];
  #pragma unroll
  for (int q = 0; q < 8; ++q) t[q] = 0.0;
  for (int b = 0; b < Bb; ++b)
    for (int q = 0; q < 8; ++q) t[q] += partials[b * 8 + q];

  int s = 0;
  for (int b = 0; b < Bb; ++b) s += num_objects[b];
  float tno = (float)s;

  float category_cost  = (float)t[0] / tno;
  float attribute_cost = (float)t[1] / tno;
  float box_cost       = (float)t[2] / tno;
  float exist_loss     = (float)t[4] / (float)(Bb * NPp);
  float total = category_cost + attribute_cost + box_cost + exist_loss;
  float iou_metric = (float)t[3] / tno;
  float npredf = (float)t[7];
  float mAP50 = (float)t[5] / npredf;
  float m5095 = (float)t[6] / (npredf * 10.0f);

  out[0] = total;
  out[1] = category_cost;
  out[2] = attribute_cost;
  out[3] = box_cost;
  out[4] = exist_loss;
  out[5] = iou_metric;
  out[6] = mAP50;
  out[7] = m5095;
}

// ---------- launcher ----------

extern "C" void kernel_launch(void* const* d_in, const int* in_sizes, int n_in,
                              void* d_out, int out_size, void* d_ws, size_t ws_size,
                              hipStream_t stream) {
  const float* category        = (const float*)d_in[0];
  const float* attribute       = (const float*)d_in[1];
  const float* bbox            = (const float*)d_in[2];
  const int*   num_objects     = (const int*)d_in[3];
  const float* cat_preds       = (const float*)d_in[4];
  const float* attribute_preds = (const float*)d_in[5];
  const float* box_preds       = (const float*)d_in[6];
  float* out = (float*)d_out;

  double* partials = (double*)d_ws;                       // 8*8 doubles = 512 B
  float*  gcost    = (float*)((char*)d_ws + 4096);        // 960000 B (fallback only)

  const int STAGED_LDS = NTt * NPp * 4 + 104 * 4;         // 120416
  const int SMALL_LDS  = 104 * 4;

  hipError_t e = hipFuncSetAttribute(
      reinterpret_cast<const void*>(&fused_kernel<true>),
      hipFuncAttributeMaxDynamicSharedMemorySize, STAGED_LDS);
  if (e == hipSuccess) {
    // diagnostic region: 8 batches x 64KB of 64B lines, at ws+4096
    float* diag = (ws_size >= (size_t)(4096 + 8 * 65536))
                      ? (float*)((char*)d_ws + 4096) : nullptr;
    fused_kernel<true><<<Bb, 256, STAGED_LDS, stream>>>(
        category, attribute, bbox, num_objects, cat_preds, attribute_preds,
        box_preds, gcost, partials, diag);
  } else {
    fused_kernel<false><<<Bb, 256, SMALL_LDS, stream>>>(
        category, attribute, bbox, num_objects, cat_preds, attribute_preds,
        box_preds, gcost, partials, (float*)nullptr);
  }

  combine_kernel<<<1, 64, 0, stream>>>(partials, num_objects, out);
}

// Round 9
// 135.093 us; speedup vs baseline: 1.4740x; 1.4038x over previous
//
#include <hip/hip_runtime.h>
#include <math.h>

#define Bb 8
#define NTt 100
#define NPp 300
#define Cc 92
#define Aa 64

// ---------- shared math helpers (f32, op-for-op like the reference) ----------

__device__ __forceinline__ void iou_giou_f(const float* bt, const float* bp,
                                           float& iou, float& giou) {
  float ay1 = bt[0], ax1 = bt[1], ay2 = bt[2], ax2 = bt[3];
  float by1 = bp[0], bx1 = bp[1], by2 = bp[2], bx2 = bp[3];
  float area_a = fmaxf(ay2 - ay1, 0.0f) * fmaxf(ax2 - ax1, 0.0f);
  float area_b = fmaxf(by2 - by1, 0.0f) * fmaxf(bx2 - bx1, 0.0f);
  float inter = fmaxf(fminf(ay2, by2) - fmaxf(ay1, by1), 0.0f) *
                fmaxf(fminf(ax2, bx2) - fmaxf(ax1, bx1), 0.0f);
  float un = area_a + area_b - inter;
  iou = (un > 0.0f) ? (inter / un) : 0.0f;
  float enc = fmaxf(fmaxf(ay2, by2) - fminf(ay1, by1), 0.0f) *
              fmaxf(fmaxf(ax2, bx2) - fminf(ax1, bx1), 0.0f);
  giou = iou - ((enc > 0.0f) ? ((enc - un) / enc) : 0.0f);
}

__device__ __forceinline__ float box_cost_f(const float* bt, const float* bp,
                                            float& iou_out) {
  float iou, giou;
  iou_giou_f(bt, bp, iou, giou);
  iou_out = iou;
  float l1 = (fabsf(bt[0] - bp[0]) + fabsf(bt[1] - bp[1]) +
              fabsf(bt[2] - bp[2]) + fabsf(bt[3] - bp[3])) * 0.25f;
  return 2.0f * (1.0f - giou) + 5.0f * l1;
}

// ---------- DPP helper: wave64 f64 min (value only, fmin), result in lane 63 ----------

template <int CTRL>
__device__ __forceinline__ void dpp_fmin64(double& val) {
  union DU { double d; int i[2]; };
  DU a; a.d = val;
  int lo = __builtin_amdgcn_update_dpp(a.i[0], a.i[0], CTRL, 0xF, 0xF, false);
  int hi = __builtin_amdgcn_update_dpp(a.i[1], a.i[1], CTRL, 0xF, 0xF, false);
  DU o; o.i[0] = lo; o.i[1] = hi;
  val = fmin(val, o.d);
}

__device__ __forceinline__ double read_u_row(double u_lo, double u_hi, int i0u) {
  int ridx = i0u - 1;
  int src = ridx & 63;
  union DU { double d; int i[2]; };
  DU a, bb, r;
  a.d = u_lo; bb.d = u_hi;
  int lo0 = __builtin_amdgcn_readlane(a.i[0], src);
  int hi0 = __builtin_amdgcn_readlane(a.i[1], src);
  int lo1 = __builtin_amdgcn_readlane(bb.i[0], src);
  int hi1 = __builtin_amdgcn_readlane(bb.i[1], src);
  bool hih = (ridx >> 6) != 0;
  r.i[0] = hih ? lo1 : lo0;
  r.i[1] = hih ? hi1 : hi0;
  return r.d;
}

__device__ __forceinline__ int sel5(int s, int a0, int a1, int a2, int a3, int a4) {
  int r = a4;
  r = (s == 3) ? a3 : r;
  r = (s == 2) ? a2 : r;
  r = (s == 1) ? a1 : r;
  r = (s == 0) ? a0 : r;
  return r;
}

// ---------- kernel A: cls + match-cost, one wave per (b,t) row (800 blocks) ----------
// Latency-bound cat_preds gathers hidden by 800-wave parallelism (R2-proven).

__global__ void __launch_bounds__(64) cost_kernel(
    const float* __restrict__ category, const float* __restrict__ bbox,
    const float* __restrict__ box_preds, const float* __restrict__ cat_preds,
    float* __restrict__ cost, int* __restrict__ cls) {
  int bt = blockIdx.x;                 // 0..799
  int b = bt / NTt;
  int lane = threadIdx.x;

  // category row is an exact one-hot -> find the 1.0 via ballot
  const float* crow = category + (size_t)bt * Cc;
  float c0 = (lane < Cc) ? crow[lane] : 0.0f;
  float c1 = (lane < Cc - 64) ? crow[lane + 64] : 0.0f;
  unsigned long long m0 = __ballot(c0 == 1.0f);
  unsigned long long m1 = __ballot(c1 == 1.0f);
  int cl = m0 ? __builtin_ctzll(m0) : (m1 ? 64 + __builtin_ctzll(m1) : 0);
  if (lane == 0) cls[bt] = cl;

  float tb[4];
  tb[0] = bbox[(size_t)bt * 4 + 0];
  tb[1] = bbox[(size_t)bt * 4 + 1];
  tb[2] = bbox[(size_t)bt * 4 + 2];
  tb[3] = bbox[(size_t)bt * 4 + 3];

  const float4* bp4 = (const float4*)(box_preds + (size_t)b * NPp * 4);
  const float* cp = cat_preds + (size_t)b * NPp * Cc + cl;
  float* crow_out = cost + (size_t)bt * NPp;

  #pragma unroll
  for (int k = 0; k < 5; ++k) {
    int p = lane + (k << 6);
    if (p < NPp) {
      float4 bpv = bp4[p];
      float pb[4] = {bpv.x, bpv.y, bpv.z, bpv.w};
      float iou;
      float bc = box_cost_f(tb, pb, iou);
      float pc = cp[(size_t)p * Cc];
      crow_out[p] = (1.0f - pc) + bc;
    }
  }
}

// ---------- kernel B: stage + JV (wave 0) + 4-wave loss reductions ----------
// Column mapping in JV: lane L (<60) owns cols j = 5L+1 .. 5L+5 (lane-contiguous
// => ctz-of-ballot = smallest j, matching np.argmin's first-min tie rule).
// JV state entirely in registers (R8-proven, exact reference trajectory).

template <bool STAGE>
__global__ void __launch_bounds__(256, 1) jv_kernel(
    const float* __restrict__ attribute, const float* __restrict__ bbox,
    const int* __restrict__ num_objects, const float* __restrict__ cat_preds,
    const float* __restrict__ attribute_preds, const float* __restrict__ box_preds,
    const float* __restrict__ gcost, const int* __restrict__ gcls,
    double* __restrict__ partials, float* __restrict__ diag) {
  extern __shared__ char smem[];
  const int b = blockIdx.x;
  const int tid = threadIdx.x;
  const int lane = tid & 63;
  const int wid = tid >> 6;

  float* lds_cost = (float*)smem;                    // 30000 f32 when STAGE
  char* tail = smem + (STAGE ? NTt * NPp * 4 : 0);
  int*    cls_l = (int*)tail;                        // 100 ints  [+0 .. +400)
  int*    pj_l  = (int*)(tail + 400);                // 304 ints  [+400 .. +1616)
  double* red   = (double*)(tail + 1616);            // 4x8 f64   [+1616 .. +1872)

  const int n = num_objects[b];
  const float* costg = gcost + (size_t)b * NTt * NPp;

  // ---- phase 0: stage cost + cls into LDS; zero pj ----
  if (STAGE) {
    const float4* s4 = (const float4*)costg;
    float4* d4 = (float4*)lds_cost;
    for (int t = tid; t < (NTt * NPp) / 4; t += 256) d4[t] = s4[t];
  }
  for (int t = tid; t < NTt; t += 256) cls_l[t] = gcls[b * NTt + t];
  for (int t = tid; t < 304; t += 256) pj_l[t] = 0;
  __syncthreads();

  const float* costb = STAGE ? lds_cost : costg;

  // ---- phase 1: vanilla JV (wave 0 only; waves 1-3 wait at the barrier) ----
  if (wid == 0) {
    long long t_jv0 = clock64();

    const double INF = __builtin_inf();
    const bool active = lane < 60;
    const int laneOff = active ? 5 * lane : 0;

    double v0 = 0.0, v1 = 0.0, v2 = 0.0, v3 = 0.0, v4 = 0.0;
    double u_lo = 0.0, u_hi = 0.0;                 // u[lane+1], u[lane+65]
    int wp0 = 0, wp1 = 0, wp2 = 0, wp3 = 0, wp4 = 0;   // (way<<7)|pj per slot

    for (int i = 1; i <= n; ++i) {
      double mv0 = INF, mv1 = INF, mv2 = INF, mv3 = INF, mv4 = INF;
      int usedmask = 0, uf = 0;
      int j0u = 0, i0u = i;

      while (true) {
        { int ridx = i0u - 1; if ((ridx & 63) == lane) uf |= 1 << (ridx >> 6); }

        const float* rowp = costb + (i0u - 1) * NPp + laneOff;
        float ca = rowp[0], cb2 = rowp[1], cc = rowp[2], cd = rowp[3], ce = rowp[4];
        double ui0 = read_u_row(u_lo, u_hi, i0u);

        // ungated scan: settled slots (mv=-INF) never update way, stay -INF
        {
          double cur = (double)ca - ui0 - v0;
          wp0 = (cur < mv0) ? ((j0u << 7) | (wp0 & 127)) : wp0;
          mv0 = fmin(mv0, cur);
        }
        {
          double cur = (double)cb2 - ui0 - v1;
          wp1 = (cur < mv1) ? ((j0u << 7) | (wp1 & 127)) : wp1;
          mv1 = fmin(mv1, cur);
        }
        {
          double cur = (double)cc - ui0 - v2;
          wp2 = (cur < mv2) ? ((j0u << 7) | (wp2 & 127)) : wp2;
          mv2 = fmin(mv2, cur);
        }
        {
          double cur = (double)cd - ui0 - v3;
          wp3 = (cur < mv3) ? ((j0u << 7) | (wp3 & 127)) : wp3;
          mv3 = fmin(mv3, cur);
        }
        {
          double cur = (double)ce - ui0 - v4;
          wp4 = (cur < mv4) ? ((j0u << 7) | (wp4 & 127)) : wp4;
          mv4 = fmin(mv4, cur);
        }

        double cv0 = (!active || (usedmask & 1))  ? INF : mv0;
        double cv1 = (!active || (usedmask & 2))  ? INF : mv1;
        double cv2 = (!active || (usedmask & 4))  ? INF : mv2;
        double cv3 = (!active || (usedmask & 8))  ? INF : mv3;
        double cv4 = (!active || (usedmask & 16)) ? INF : mv4;

        double m01 = fmin(fmin(fmin(cv0, cv1), fmin(cv2, cv3)), cv4);

        int k0 = (cv3 == m01) ? 3 : 4;
        k0 = (cv2 == m01) ? 2 : k0;
        k0 = (cv1 == m01) ? 1 : k0;
        k0 = (cv0 == m01) ? 0 : k0;
        int ploc = sel5(k0, wp0 & 127, wp1 & 127, wp2 & 127, wp3 & 127, wp4 & 127);
        int p01 = ((laneOff + k0 + 1) << 7) | ploc;

        double mvred = m01;
        dpp_fmin64<0x111>(mvred);   // row_shr:1
        dpp_fmin64<0x112>(mvred);   // row_shr:2
        dpp_fmin64<0x114>(mvred);   // row_shr:4
        dpp_fmin64<0x118>(mvred);   // row_shr:8
        dpp_fmin64<0x142>(mvred);   // row_bcast:15
        dpp_fmin64<0x143>(mvred);   // row_bcast:31
        union DU { double d; int i[2]; };
        DU w; w.d = mvred;
        DU r;
        r.i[0] = __builtin_amdgcn_readlane(w.i[0], 63);
        r.i[1] = __builtin_amdgcn_readlane(w.i[1], 63);
        double delta = r.d;

        unsigned long long hit = __ballot(m01 == delta);
        int winlane = __builtin_ctzll(hit);
        int wpk = __builtin_amdgcn_readlane(p01, winlane);
        int j1u = wpk >> 7, i1u = wpk & 127;

        if (uf & 1) u_lo += delta;
        if (uf & 2) u_hi += delta;
        v0 -= (usedmask & 1)  ? delta : 0.0;
        v1 -= (usedmask & 2)  ? delta : 0.0;
        v2 -= (usedmask & 4)  ? delta : 0.0;
        v3 -= (usedmask & 8)  ? delta : 0.0;
        v4 -= (usedmask & 16) ? delta : 0.0;
        mv0 -= delta; mv1 -= delta; mv2 -= delta; mv3 -= delta; mv4 -= delta;

        int jm = j1u - 1;
        int wl = jm / 5;
        int sk = jm - 5 * wl;
        if (lane == wl) {
          usedmask |= 1 << sk;
          if      (sk == 0) mv0 = -INF;
          else if (sk == 1) mv1 = -INF;
          else if (sk == 2) mv2 = -INF;
          else if (sk == 3) mv3 = -INF;
          else              mv4 = -INF;
        }

        j0u = j1u; i0u = i1u;
        if (i0u == 0) break;
      }

      // augment alternating path (uniform readlane walk)
      {
        int jj = j0u;
        int idx = jj - 1;
        int owner = idx / 5;
        int slot = idx - 5 * owner;
        int f0 = __builtin_amdgcn_readlane(wp0, owner),
            f1 = __builtin_amdgcn_readlane(wp1, owner),
            f2 = __builtin_amdgcn_readlane(wp2, owner),
            f3 = __builtin_amdgcn_readlane(wp3, owner),
            f4 = __builtin_amdgcn_readlane(wp4, owner);
        int wpv = sel5(slot, f0, f1, f2, f3, f4);
        int wayv = wpv >> 7;

        while (true) {
          int jp = wayv;                        // uniform
          int newv;
          int wayn = 0;
          if (jp != 0) {
            int idx2 = jp - 1;
            int owner2 = idx2 / 5;
            int slot2 = idx2 - 5 * owner2;
            int g0 = __builtin_amdgcn_readlane(wp0, owner2),
                g1 = __builtin_amdgcn_readlane(wp1, owner2),
                g2 = __builtin_amdgcn_readlane(wp2, owner2),
                g3 = __builtin_amdgcn_readlane(wp3, owner2),
                g4 = __builtin_amdgcn_readlane(wp4, owner2);
            int wpn = sel5(slot2, g0, g1, g2, g3, g4);
            wayn = wpn >> 7;
            newv = wpn & 127;                   // old pj[jp]
          } else {
            newv = i;
          }
          if (lane == owner) {
            if      (slot == 0) wp0 = (wp0 & ~127) | newv;
            else if (slot == 1) wp1 = (wp1 & ~127) | newv;
            else if (slot == 2) wp2 = (wp2 & ~127) | newv;
            else if (slot == 3) wp3 = (wp3 & ~127) | newv;
            else                wp4 = (wp4 & ~127) | newv;
          }
          if (jp == 0) break;
          jj = jp;
          idx = jj - 1;
          owner = idx / 5;
          slot = idx - 5 * owner;
          wayv = wayn;
        }
      }
    }

    long long t_jv1 = clock64();

    // export assignment to LDS for all waves
    if (active) {
      pj_l[5 * lane + 1] = wp0 & 127;
      pj_l[5 * lane + 2] = wp1 & 127;
      pj_l[5 * lane + 3] = wp2 & 127;
      pj_l[5 * lane + 4] = wp3 & 127;
      pj_l[5 * lane + 5] = wp4 & 127;
    }

    // diagnostic: JV-phase cycles -> WRITE_SIZE (64B lines of 4096-cy units)
    if (diag != nullptr && lane == 0) {
      int nl = (int)((t_jv1 - t_jv0) >> 12);
      if (nl > 1024) nl = 1024;
      for (int w2 = 0; w2 < nl; ++w2)
        __builtin_nontemporal_store(1.0f, diag + ((b << 14) + (w2 << 4)));
    }
  }
  __syncthreads();

  // ---- phase 2: per-batch loss reductions (ALL 4 waves) ----
  double acc[7];
  #pragma unroll
  for (int q = 0; q < 7; ++q) acc[q] = 0.0;
  // 0 cat, 1 attr, 2 box, 3 iou, 4 exist, 5 cnt50, 6 cntall

  const float EPSF = 1e-7f;
  const float HIF  = (float)(1.0 - 1e-7);

  for (int j = tid; j < NPp; j += 256) {
    int prowv = pj_l[j + 1];
    if (prowv != 0) {
      int t = prowv - 1;
      int bt = b * NTt + t;
      int idx = b * NPp + j;

      float pc = cat_preds[(size_t)idx * Cc + cls_l[t]];
      acc[0] += (double)(-logf(pc + 1e-5f));

      const float4* yrow4 = (const float4*)(attribute + (size_t)bt * Aa);
      const float4* prw4  = (const float4*)(attribute_preds + (size_t)idx * Aa);
      float af = 0.0f;
      #pragma unroll 4
      for (int a4 = 0; a4 < Aa / 4; ++a4) {
        float4 yv = yrow4[a4];
        float4 pv = prw4[a4];
        float ys[4] = {yv.x, yv.y, yv.z, yv.w};
        float ps[4] = {pv.x, pv.y, pv.z, pv.w};
        #pragma unroll
        for (int e = 0; e < 4; ++e) {
          float y = ys[e];
          float p = fminf(fmaxf(ps[e], EPSF), HIF);
          float cev = -(y * logf(p) + (1.0f - y) * logf(1.0f - p));
          float pt = y * p + (1.0f - y) * (1.0f - p);
          float alpha = y * 0.25f + (1.0f - y) * 0.75f;
          float om = 1.0f - pt;
          af += alpha * (om * om) * cev;
        }
      }
      acc[1] += (double)af;

      const float* btp = bbox + (size_t)bt * 4;
      const float* bpp = box_preds + (size_t)idx * 4;
      float iou;
      float bc = box_cost_f(btp, bpp, iou);
      acc[2] += (double)bc;
      float ia = 1.0f - iou;
      acc[3] += (double)ia;
      if (ia >= 0.5f) acc[5] += 1.0;
      for (int rr = 50; rr < 100; rr += 5) {
        float thr = (float)((double)rr / 100.0);
        if (ia >= thr) acc[6] += 1.0;
      }

      float yp = 1.0f - cat_preds[(size_t)idx * Cc + 0];
      float pn = yp / yp;
      pn = fminf(fmaxf(pn, EPSF), HIF);
      acc[4] += (double)(-logf(pn));
    }
  }

  // per-wave reduce, then fixed-order cross-wave combine
  #pragma unroll
  for (int q = 0; q < 7; ++q) {
    #pragma unroll
    for (int off = 32; off >= 1; off >>= 1) acc[q] += __shfl_xor(acc[q], off);
  }
  if (lane == 0) {
    #pragma unroll
    for (int q = 0; q < 7; ++q) red[wid * 8 + q] = acc[q];
  }

  // num_predicted contribution (wave 0): count cat_preds[b,1,:] < 0.5
  if (wid == 0) {
    const float* cpb1 = cat_preds + ((size_t)b * NPp + 1) * Cc;
    float q0 = (lane < Cc) ? cpb1[lane] : 1.0f;
    float q1 = (lane + 64 < Cc) ? cpb1[lane + 64] : 1.0f;
    unsigned long long mm0 = __ballot(q0 < 0.5f);
    unsigned long long mm1 = __ballot(q1 < 0.5f);
    if (lane == 0) partials[b * 8 + 7] = (double)(__popcll(mm0) + __popcll(mm1));
  }
  __syncthreads();

  if (tid == 0) {
    #pragma unroll
    for (int q = 0; q < 7; ++q) {
      double s = 0.0;
      for (int w2 = 0; w2 < 4; ++w2) s += red[w2 * 8 + q];
      partials[b * 8 + q] = s;
    }
  }
}

// ---------- combine kernel: fixed-order sum of 8 batches -> 8 outputs ----------

__global__ void combine_kernel(const double* __restrict__ partials,
                               const int* __restrict__ num_objects,
                               float* __restrict__ out) {
  if (threadIdx.x != 0) return;
  double t[8];
  #pragma unroll
  for (int q = 0; q < 8; ++q) t[q] = 0.0;
  for (int b = 0; b < Bb; ++b)
    for (int q = 0; q < 8; ++q) t[q] += partials[b * 8 + q];

  int s = 0;
  for (int b = 0; b < Bb; ++b) s += num_objects[b];
  float tno = (float)s;

  float category_cost  = (float)t[0] / tno;
  float attribute_cost = (float)t[1] / tno;
  float box_cost       = (float)t[2] / tno;
  float exist_loss     = (float)t[4] / (float)(Bb * NPp);
  float total = category_cost + attribute_cost + box_cost + exist_loss;
  float iou_metric = (float)t[3] / tno;
  float npredf = (float)t[7];
  float mAP50 = (float)t[5] / npredf;
  float m5095 = (float)t[6] / (npredf * 10.0f);

  out[0] = total;
  out[1] = category_cost;
  out[2] = attribute_cost;
  out[3] = box_cost;
  out[4] = exist_loss;
  out[5] = iou_metric;
  out[6] = mAP50;
  out[7] = m5095;
}

// ---------- launcher ----------

extern "C" void kernel_launch(void* const* d_in, const int* in_sizes, int n_in,
                              void* d_out, int out_size, void* d_ws, size_t ws_size,
                              hipStream_t stream) {
  const float* category        = (const float*)d_in[0];
  const float* attribute       = (const float*)d_in[1];
  const float* bbox            = (const float*)d_in[2];
  const int*   num_objects     = (const int*)d_in[3];
  const float* cat_preds       = (const float*)d_in[4];
  const float* attribute_preds = (const float*)d_in[5];
  const float* box_preds       = (const float*)d_in[6];
  float* out = (float*)d_out;

  double* partials = (double*)d_ws;                       //      0 ..    512
  int*    gcls     = (int*)((char*)d_ws + 512);           //    512 ..   3712
  float*  gcost    = (float*)((char*)d_ws + 4096);        //   4096 .. 964096

  // diagnostic region: 8 batches x 64KB of 64B lines
  const size_t DIAG_OFF = 970752;
  float* diag = (ws_size >= DIAG_OFF + (size_t)8 * 65536)
                    ? (float*)((char*)d_ws + DIAG_OFF) : nullptr;

  cost_kernel<<<Bb * NTt, 64, 0, stream>>>(category, bbox, box_preds, cat_preds,
                                           gcost, gcls);

  const int STAGED_LDS = NTt * NPp * 4 + 1872;            // 121872
  const int SMALL_LDS  = 1872;

  hipError_t e = hipFuncSetAttribute(
      reinterpret_cast<const void*>(&jv_kernel<true>),
      hipFuncAttributeMaxDynamicSharedMemorySize, STAGED_LDS);
  if (e == hipSuccess) {
    jv_kernel<true><<<Bb, 256, STAGED_LDS, stream>>>(
        attribute, bbox, num_objects, cat_preds, attribute_preds, box_preds,
        gcost, gcls, partials, diag);
  } else {
    jv_kernel<false><<<Bb, 256, SMALL_LDS, stream>>>(
        attribute, bbox, num_objects, cat_preds, attribute_preds, box_preds,
        gcost, gcls, partials, (float*)nullptr);
  }

  combine_kernel<<<1, 64, 0, stream>>>(partials, num_objects, out);
}

// Round 10
// 112.577 us; speedup vs baseline: 1.7688x; 1.2000x over previous
//
#include <hip/hip_runtime.h>
#include <math.h>

#define Bb 8
#define NTt 100
#define NPp 300
#define Cc 92
#define Aa 64

// ---------- shared math helpers (f32, op-for-op like the reference) ----------

__device__ __forceinline__ void iou_giou_f(const float* bt, const float* bp,
                                           float& iou, float& giou) {
  float ay1 = bt[0], ax1 = bt[1], ay2 = bt[2], ax2 = bt[3];
  float by1 = bp[0], bx1 = bp[1], by2 = bp[2], bx2 = bp[3];
  float area_a = fmaxf(ay2 - ay1, 0.0f) * fmaxf(ax2 - ax1, 0.0f);
  float area_b = fmaxf(by2 - by1, 0.0f) * fmaxf(bx2 - bx1, 0.0f);
  float inter = fmaxf(fminf(ay2, by2) - fmaxf(ay1, by1), 0.0f) *
                fmaxf(fminf(ax2, bx2) - fmaxf(ax1, bx1), 0.0f);
  float un = area_a + area_b - inter;
  iou = (un > 0.0f) ? (inter / un) : 0.0f;
  float enc = fmaxf(fmaxf(ay2, by2) - fminf(ay1, by1), 0.0f) *
              fmaxf(fmaxf(ax2, bx2) - fminf(ax1, bx1), 0.0f);
  giou = iou - ((enc > 0.0f) ? ((enc - un) / enc) : 0.0f);
}

__device__ __forceinline__ float box_cost_f(const float* bt, const float* bp,
                                            float& iou_out) {
  float iou, giou;
  iou_giou_f(bt, bp, iou, giou);
  iou_out = iou;
  float l1 = (fabsf(bt[0] - bp[0]) + fabsf(bt[1] - bp[1]) +
              fabsf(bt[2] - bp[2]) + fabsf(bt[3] - bp[3])) * 0.25f;
  return 2.0f * (1.0f - giou) + 5.0f * l1;
}

// ---------- DPP helper: wave64 f64 min (value only, fmin), result in lane 63 ----------

template <int CTRL>
__device__ __forceinline__ void dpp_fmin64(double& val) {
  union DU { double d; int i[2]; };
  DU a; a.d = val;
  int lo = __builtin_amdgcn_update_dpp(a.i[0], a.i[0], CTRL, 0xF, 0xF, false);
  int hi = __builtin_amdgcn_update_dpp(a.i[1], a.i[1], CTRL, 0xF, 0xF, false);
  DU o; o.i[0] = lo; o.i[1] = hi;
  val = fmin(val, o.d);
}

__device__ __forceinline__ double wave_fmin64_bcast(double m01) {
  double mvred = m01;
  dpp_fmin64<0x111>(mvred);   // row_shr:1
  dpp_fmin64<0x112>(mvred);   // row_shr:2
  dpp_fmin64<0x114>(mvred);   // row_shr:4
  dpp_fmin64<0x118>(mvred);   // row_shr:8
  dpp_fmin64<0x142>(mvred);   // row_bcast:15
  dpp_fmin64<0x143>(mvred);   // row_bcast:31
  union DU { double d; int i[2]; };
  DU w; w.d = mvred;
  DU r;
  r.i[0] = __builtin_amdgcn_readlane(w.i[0], 63);
  r.i[1] = __builtin_amdgcn_readlane(w.i[1], 63);
  return r.d;
}

__device__ __forceinline__ double read_u_row(double u_lo, double u_hi, int i0u) {
  int ridx = i0u - 1;
  int src = ridx & 63;
  union DU { double d; int i[2]; };
  DU a, bb, r;
  a.d = u_lo; bb.d = u_hi;
  int lo0 = __builtin_amdgcn_readlane(a.i[0], src);
  int hi0 = __builtin_amdgcn_readlane(a.i[1], src);
  int lo1 = __builtin_amdgcn_readlane(bb.i[0], src);
  int hi1 = __builtin_amdgcn_readlane(bb.i[1], src);
  bool hih = (ridx >> 6) != 0;
  r.i[0] = hih ? lo1 : lo0;
  r.i[1] = hih ? hi1 : hi0;
  return r.d;
}

__device__ __forceinline__ int sel5(int s, int a0, int a1, int a2, int a3, int a4) {
  int r = a4;
  r = (s == 3) ? a3 : r;
  r = (s == 2) ? a2 : r;
  r = (s == 1) ? a1 : r;
  r = (s == 0) ? a0 : r;
  return r;
}

// ---------- kernel A: cls + match-cost, one wave per (b,t) row (800 blocks) ----------

__global__ void __launch_bounds__(64) cost_kernel(
    const float* __restrict__ category, const float* __restrict__ bbox,
    const float* __restrict__ box_preds, const float* __restrict__ cat_preds,
    float* __restrict__ cost, int* __restrict__ cls) {
  int bt = blockIdx.x;                 // 0..799
  int b = bt / NTt;
  int lane = threadIdx.x;

  const float* crow = category + (size_t)bt * Cc;
  float c0 = (lane < Cc) ? crow[lane] : 0.0f;
  float c1 = (lane < Cc - 64) ? crow[lane + 64] : 0.0f;
  unsigned long long m0 = __ballot(c0 == 1.0f);
  unsigned long long m1 = __ballot(c1 == 1.0f);
  int cl = m0 ? __builtin_ctzll(m0) : (m1 ? 64 + __builtin_ctzll(m1) : 0);
  if (lane == 0) cls[bt] = cl;

  float tb[4];
  tb[0] = bbox[(size_t)bt * 4 + 0];
  tb[1] = bbox[(size_t)bt * 4 + 1];
  tb[2] = bbox[(size_t)bt * 4 + 2];
  tb[3] = bbox[(size_t)bt * 4 + 3];

  const float4* bp4 = (const float4*)(box_preds + (size_t)b * NPp * 4);
  const float* cp = cat_preds + (size_t)b * NPp * Cc + cl;
  float* crow_out = cost + (size_t)bt * NPp;

  #pragma unroll
  for (int k = 0; k < 5; ++k) {
    int p = lane + (k << 6);
    if (p < NPp) {
      float4 bpv = bp4[p];
      float pb[4] = {bpv.x, bpv.y, bpv.z, bpv.w};
      float iou;
      float bc = box_cost_f(tb, pb, iou);
      float pc = cp[(size_t)p * Cc];
      crow_out[p] = (1.0f - pc) + bc;
    }
  }
}

// ---------- kernel B: stage + JV (wave 0, fast-path) + 4-wave loss reductions ----------
// Column mapping in JV: lane L (<60) owns cols j = 5L+1 .. 5L+5 (lane-contiguous
// => ctz-of-ballot = smallest j, matching np.argmin's first-min tie rule).
// FAST PATH (exact): row i's first Dijkstra iteration has u[i]=0, used={}, so
// minv[j] = (double)c[i][j] - v[j] identically. Wave-argmin; if the winning
// column is FREE (p==0, the ~99% case per R7 instrument), the reference's full
// iteration-1 collapses to {p[j1]=i; u[i]=delta} (way/minv/v[0] effects dead).
// Otherwise fall back to the bit-exact full Dijkstra loop, restarted cleanly
// (the fast attempt has zero side effects).

template <bool STAGE>
__global__ void __launch_bounds__(256, 1) jv_kernel(
    const float* __restrict__ attribute, const float* __restrict__ bbox,
    const int* __restrict__ num_objects, const float* __restrict__ cat_preds,
    const float* __restrict__ attribute_preds, const float* __restrict__ box_preds,
    const float* __restrict__ gcost, const int* __restrict__ gcls,
    double* __restrict__ partials, float* __restrict__ diag) {
  extern __shared__ char smem[];
  const int b = blockIdx.x;
  const int tid = threadIdx.x;
  const int lane = tid & 63;
  const int wid = tid >> 6;

  float* lds_cost = (float*)smem;                    // 30000 f32 when STAGE
  char* tail = smem + (STAGE ? NTt * NPp * 4 : 0);
  int*    cls_l = (int*)tail;                        // 100 ints
  int*    pj_l  = (int*)(tail + 400);                // 304 ints
  double* red   = (double*)(tail + 1616);            // 4x8 f64

  const int n = num_objects[b];
  const float* costg = gcost + (size_t)b * NTt * NPp;

  // ---- phase 0: stage n cost rows + cls into LDS; zero pj ----
  if (STAGE) {
    const float4* s4 = (const float4*)costg;
    float4* d4 = (float4*)lds_cost;
    int n4 = n * (NPp / 4);                          // 300/4 = 75 per row
    for (int t = tid; t < n4; t += 256) d4[t] = s4[t];
  }
  for (int t = tid; t < NTt; t += 256) cls_l[t] = gcls[b * NTt + t];
  for (int t = tid; t < 304; t += 256) pj_l[t] = 0;
  __syncthreads();

  const float* costb = STAGE ? lds_cost : costg;

  // ---- phase 1: JV (wave 0 only; waves 1-3 wait at the barrier) ----
  if (wid == 0) {
    long long t_jv0 = clock64();

    const double INF = __builtin_inf();
    const bool active = lane < 60;
    const int laneOff = active ? 5 * lane : 0;

    double v0 = 0.0, v1 = 0.0, v2 = 0.0, v3 = 0.0, v4 = 0.0;
    double u_lo = 0.0, u_hi = 0.0;                 // u[lane+1], u[lane+65]
    int wp0 = 0, wp1 = 0, wp2 = 0, wp3 = 0, wp4 = 0;   // (way<<7)|pj per slot

    // prefetch row 1
    float pca = costb[laneOff], pcb = costb[laneOff + 1], pcc = costb[laneOff + 2],
          pcd = costb[laneOff + 3], pce = costb[laneOff + 4];

    for (int i = 1; i <= n; ++i) {
      float ca = pca, cb2 = pcb, cc = pcc, cd = pcd, ce = pce;
      if (i < n) {                                 // prefetch row i+1
        const float* nr = costb + i * NPp + laneOff;
        pca = nr[0]; pcb = nr[1]; pcc = nr[2]; pcd = nr[3]; pce = nr[4];
      }

      // ---- fast path: key[j] = (double)c - v[j]  (== reference minv, u[i]=0) ----
      double fk0 = (double)ca - v0;
      double fk1 = (double)cb2 - v1;
      double fk2 = (double)cc - v2;
      double fk3 = (double)cd - v3;
      double fk4 = (double)ce - v4;
      double cv0 = active ? fk0 : INF;
      double cv1 = active ? fk1 : INF;
      double cv2 = active ? fk2 : INF;
      double cv3 = active ? fk3 : INF;
      double cv4 = active ? fk4 : INF;

      double m01 = fmin(fmin(fmin(cv0, cv1), fmin(cv2, cv3)), cv4);
      int k0 = (cv3 == m01) ? 3 : 4;
      k0 = (cv2 == m01) ? 2 : k0;
      k0 = (cv1 == m01) ? 1 : k0;
      k0 = (cv0 == m01) ? 0 : k0;
      int ploc = sel5(k0, wp0 & 127, wp1 & 127, wp2 & 127, wp3 & 127, wp4 & 127);
      int p01 = ((laneOff + k0 + 1) << 7) | ploc;

      double delta = wave_fmin64_bcast(m01);
      unsigned long long hit = __ballot(m01 == delta);
      int winlane = __builtin_ctzll(hit);
      int wpk = __builtin_amdgcn_readlane(p01, winlane);
      int j1u = wpk >> 7, i1u = wpk & 127;

      if (i1u == 0) {
        // free column: assign + u[i] = delta (exact collapse of iteration 1)
        int jm = j1u - 1;
        int wl = jm / 5;
        int sk = jm - 5 * wl;
        if (lane == wl) {
          if      (sk == 0) wp0 = (wp0 & ~127) | i;
          else if (sk == 1) wp1 = (wp1 & ~127) | i;
          else if (sk == 2) wp2 = (wp2 & ~127) | i;
          else if (sk == 3) wp3 = (wp3 & ~127) | i;
          else              wp4 = (wp4 & ~127) | i;
        }
        int ridx = i - 1;
        if ((ridx & 63) == lane) {
          if ((ridx >> 6) == 0) u_lo += delta; else u_hi += delta;
        }
        continue;
      }

      // ---- fallback: full bit-exact Dijkstra for this row (fresh start) ----
      double mv0 = INF, mv1 = INF, mv2 = INF, mv3 = INF, mv4 = INF;
      int usedmask = 0, uf = 0;
      int j0u = 0, i0u = i;

      while (true) {
        { int ridx = i0u - 1; if ((ridx & 63) == lane) uf |= 1 << (ridx >> 6); }

        const float* rowp = costb + (i0u - 1) * NPp + laneOff;
        float fa = rowp[0], fb = rowp[1], fc = rowp[2], fd = rowp[3], fe = rowp[4];
        double ui0 = read_u_row(u_lo, u_hi, i0u);

        {
          double cur = (double)fa - ui0 - v0;
          wp0 = (cur < mv0) ? ((j0u << 7) | (wp0 & 127)) : wp0;
          mv0 = fmin(mv0, cur);
        }
        {
          double cur = (double)fb - ui0 - v1;
          wp1 = (cur < mv1) ? ((j0u << 7) | (wp1 & 127)) : wp1;
          mv1 = fmin(mv1, cur);
        }
        {
          double cur = (double)fc - ui0 - v2;
          wp2 = (cur < mv2) ? ((j0u << 7) | (wp2 & 127)) : wp2;
          mv2 = fmin(mv2, cur);
        }
        {
          double cur = (double)fd - ui0 - v3;
          wp3 = (cur < mv3) ? ((j0u << 7) | (wp3 & 127)) : wp3;
          mv3 = fmin(mv3, cur);
        }
        {
          double cur = (double)fe - ui0 - v4;
          wp4 = (cur < mv4) ? ((j0u << 7) | (wp4 & 127)) : wp4;
          mv4 = fmin(mv4, cur);
        }

        double dv0 = (!active || (usedmask & 1))  ? INF : mv0;
        double dv1 = (!active || (usedmask & 2))  ? INF : mv1;
        double dv2 = (!active || (usedmask & 4))  ? INF : mv2;
        double dv3 = (!active || (usedmask & 8))  ? INF : mv3;
        double dv4 = (!active || (usedmask & 16)) ? INF : mv4;

        double mm = fmin(fmin(fmin(dv0, dv1), fmin(dv2, dv3)), dv4);
        int kk = (dv3 == mm) ? 3 : 4;
        kk = (dv2 == mm) ? 2 : kk;
        kk = (dv1 == mm) ? 1 : kk;
        kk = (dv0 == mm) ? 0 : kk;
        int pl2 = sel5(kk, wp0 & 127, wp1 & 127, wp2 & 127, wp3 & 127, wp4 & 127);
        int pk2 = ((laneOff + kk + 1) << 7) | pl2;

        double delta2 = wave_fmin64_bcast(mm);
        unsigned long long hit2 = __ballot(mm == delta2);
        int winlane2 = __builtin_ctzll(hit2);
        int wpk2 = __builtin_amdgcn_readlane(pk2, winlane2);
        int j1b = wpk2 >> 7, i1b = wpk2 & 127;

        if (uf & 1) u_lo += delta2;
        if (uf & 2) u_hi += delta2;
        v0 -= (usedmask & 1)  ? delta2 : 0.0;
        v1 -= (usedmask & 2)  ? delta2 : 0.0;
        v2 -= (usedmask & 4)  ? delta2 : 0.0;
        v3 -= (usedmask & 8)  ? delta2 : 0.0;
        v4 -= (usedmask & 16) ? delta2 : 0.0;
        mv0 -= delta2; mv1 -= delta2; mv2 -= delta2; mv3 -= delta2; mv4 -= delta2;

        int jm = j1b - 1;
        int wl = jm / 5;
        int sk = jm - 5 * wl;
        if (lane == wl) {
          usedmask |= 1 << sk;
          if      (sk == 0) mv0 = -INF;
          else if (sk == 1) mv1 = -INF;
          else if (sk == 2) mv2 = -INF;
          else if (sk == 3) mv3 = -INF;
          else              mv4 = -INF;
        }

        j0u = j1b; i0u = i1b;
        if (i0u == 0) break;
      }

      // augment alternating path (uniform readlane walk)
      {
        int jj = j0u;
        int idx = jj - 1;
        int owner = idx / 5;
        int slot = idx - 5 * owner;
        int f0 = __builtin_amdgcn_readlane(wp0, owner),
            f1 = __builtin_amdgcn_readlane(wp1, owner),
            f2 = __builtin_amdgcn_readlane(wp2, owner),
            f3 = __builtin_amdgcn_readlane(wp3, owner),
            f4 = __builtin_amdgcn_readlane(wp4, owner);
        int wpv = sel5(slot, f0, f1, f2, f3, f4);
        int wayv = wpv >> 7;

        while (true) {
          int jp = wayv;                        // uniform
          int newv;
          int wayn = 0;
          if (jp != 0) {
            int idx2 = jp - 1;
            int owner2 = idx2 / 5;
            int slot2 = idx2 - 5 * owner2;
            int g0 = __builtin_amdgcn_readlane(wp0, owner2),
                g1 = __builtin_amdgcn_readlane(wp1, owner2),
                g2 = __builtin_amdgcn_readlane(wp2, owner2),
                g3 = __builtin_amdgcn_readlane(wp3, owner2),
                g4 = __builtin_amdgcn_readlane(wp4, owner2);
            int wpn = sel5(slot2, g0, g1, g2, g3, g4);
            wayn = wpn >> 7;
            newv = wpn & 127;                   // old pj[jp]
          } else {
            newv = i;
          }
          if (lane == owner) {
            if      (slot == 0) wp0 = (wp0 & ~127) | newv;
            else if (slot == 1) wp1 = (wp1 & ~127) | newv;
            else if (slot == 2) wp2 = (wp2 & ~127) | newv;
            else if (slot == 3) wp3 = (wp3 & ~127) | newv;
            else                wp4 = (wp4 & ~127) | newv;
          }
          if (jp == 0) break;
          jj = jp;
          idx = jj - 1;
          owner = idx / 5;
          slot = idx - 5 * owner;
          wayv = wayn;
        }
      }
    }

    long long t_jv1 = clock64();

    // export assignment to LDS for all waves
    if (active) {
      pj_l[5 * lane + 1] = wp0 & 127;
      pj_l[5 * lane + 2] = wp1 & 127;
      pj_l[5 * lane + 3] = wp2 & 127;
      pj_l[5 * lane + 4] = wp3 & 127;
      pj_l[5 * lane + 5] = wp4 & 127;
    }

    // diagnostic: JV-phase cycles -> WRITE_SIZE (64B lines of 4096-cy units)
    if (diag != nullptr && lane == 0) {
      int nl = (int)((t_jv1 - t_jv0) >> 12);
      if (nl > 1024) nl = 1024;
      for (int w2 = 0; w2 < nl; ++w2)
        __builtin_nontemporal_store(1.0f, diag + ((b << 14) + (w2 << 4)));
    }
  }
  __syncthreads();

  // ---- phase 2: per-batch loss reductions (ALL 4 waves) ----
  double acc[7];
  #pragma unroll
  for (int q = 0; q < 7; ++q) acc[q] = 0.0;
  // 0 cat, 1 attr, 2 box, 3 iou, 4 exist, 5 cnt50, 6 cntall

  const float EPSF = 1e-7f;
  const float HIF  = (float)(1.0 - 1e-7);

  for (int j = tid; j < NPp; j += 256) {
    int prowv = pj_l[j + 1];
    if (prowv != 0) {
      int t = prowv - 1;
      int bt = b * NTt + t;
      int idx = b * NPp + j;

      float pc = cat_preds[(size_t)idx * Cc + cls_l[t]];
      acc[0] += (double)(-logf(pc + 1e-5f));

      const float4* yrow4 = (const float4*)(attribute + (size_t)bt * Aa);
      const float4* prw4  = (const float4*)(attribute_preds + (size_t)idx * Aa);
      float af = 0.0f;
      #pragma unroll 4
      for (int a4 = 0; a4 < Aa / 4; ++a4) {
        float4 yv = yrow4[a4];
        float4 pv = prw4[a4];
        float ys[4] = {yv.x, yv.y, yv.z, yv.w};
        float ps[4] = {pv.x, pv.y, pv.z, pv.w};
        #pragma unroll
        for (int e = 0; e < 4; ++e) {
          float y = ys[e];
          float p = fminf(fmaxf(ps[e], EPSF), HIF);
          float cev = -(y * logf(p) + (1.0f - y) * logf(1.0f - p));
          float pt = y * p + (1.0f - y) * (1.0f - p);
          float alpha = y * 0.25f + (1.0f - y) * 0.75f;
          float om = 1.0f - pt;
          af += alpha * (om * om) * cev;
        }
      }
      acc[1] += (double)af;

      const float* btp = bbox + (size_t)bt * 4;
      const float* bpp = box_preds + (size_t)idx * 4;
      float iou;
      float bc = box_cost_f(btp, bpp, iou);
      acc[2] += (double)bc;
      float ia = 1.0f - iou;
      acc[3] += (double)ia;
      if (ia >= 0.5f) acc[5] += 1.0;
      for (int rr = 50; rr < 100; rr += 5) {
        float thr = (float)((double)rr / 100.0);
        if (ia >= thr) acc[6] += 1.0;
      }

      float yp = 1.0f - cat_preds[(size_t)idx * Cc + 0];
      float pn = yp / yp;
      pn = fminf(fmaxf(pn, EPSF), HIF);
      acc[4] += (double)(-logf(pn));
    }
  }

  #pragma unroll
  for (int q = 0; q < 7; ++q) {
    #pragma unroll
    for (int off = 32; off >= 1; off >>= 1) acc[q] += __shfl_xor(acc[q], off);
  }
  if (lane == 0) {
    #pragma unroll
    for (int q = 0; q < 7; ++q) red[wid * 8 + q] = acc[q];
  }

  if (wid == 0) {
    const float* cpb1 = cat_preds + ((size_t)b * NPp + 1) * Cc;
    float q0 = (lane < Cc) ? cpb1[lane] : 1.0f;
    float q1 = (lane + 64 < Cc) ? cpb1[lane + 64] : 1.0f;
    unsigned long long mm0 = __ballot(q0 < 0.5f);
    unsigned long long mm1 = __ballot(q1 < 0.5f);
    if (lane == 0) partials[b * 8 + 7] = (double)(__popcll(mm0) + __popcll(mm1));
  }
  __syncthreads();

  if (tid == 0) {
    #pragma unroll
    for (int q = 0; q < 7; ++q) {
      double s = 0.0;
      for (int w2 = 0; w2 < 4; ++w2) s += red[w2 * 8 + q];
      partials[b * 8 + q] = s;
    }
  }
}

// ---------- combine kernel: fixed-order sum of 8 batches -> 8 outputs ----------

__global__ void combine_kernel(const double* __restrict__ partials,
                               const int* __restrict__ num_objects,
                               float* __restrict__ out) {
  if (threadIdx.x != 0) return;
  double t[8];
  #pragma unroll
  for (int q = 0; q < 8; ++q) t[q] = 0.0;
  for (int b = 0; b < Bb; ++b)
    for (int q = 0; q < 8; ++q) t[q] += partials[b * 8 + q];

  int s = 0;
  for (int b = 0; b < Bb; ++b) s += num_objects[b];
  float tno = (float)s;

  float category_cost  = (float)t[0] / tno;
  float attribute_cost = (float)t[1] / tno;
  float box_cost       = (float)t[2] / tno;
  float exist_loss     = (float)t[4] / (float)(Bb * NPp);
  float total = category_cost + attribute_cost + box_cost + exist_loss;
  float iou_metric = (float)t[3] / tno;
  float npredf = (float)t[7];
  float mAP50 = (float)t[5] / npredf;
  float m5095 = (float)t[6] / (npredf * 10.0f);

  out[0] = total;
  out[1] = category_cost;
  out[2] = attribute_cost;
  out[3] = box_cost;
  out[4] = exist_loss;
  out[5] = iou_metric;
  out[6] = mAP50;
  out[7] = m5095;
}

// ---------- launcher ----------

extern "C" void kernel_launch(void* const* d_in, const int* in_sizes, int n_in,
                              void* d_out, int out_size, void* d_ws, size_t ws_size,
                              hipStream_t stream) {
  const float* category        = (const float*)d_in[0];
  const float* attribute       = (const float*)d_in[1];
  const float* bbox            = (const float*)d_in[2];
  const int*   num_objects     = (const int*)d_in[3];
  const float* cat_preds       = (const float*)d_in[4];
  const float* attribute_preds = (const float*)d_in[5];
  const float* box_preds       = (const float*)d_in[6];
  float* out = (float*)d_out;

  double* partials = (double*)d_ws;                       //      0 ..    512
  int*    gcls     = (int*)((char*)d_ws + 512);           //    512 ..   3712
  float*  gcost    = (float*)((char*)d_ws + 4096);        //   4096 .. 964096

  const size_t DIAG_OFF = 970752;
  float* diag = (ws_size >= DIAG_OFF + (size_t)8 * 65536)
                    ? (float*)((char*)d_ws + DIAG_OFF) : nullptr;

  cost_kernel<<<Bb * NTt, 64, 0, stream>>>(category, bbox, box_preds, cat_preds,
                                           gcost, gcls);

  const int STAGED_LDS = NTt * NPp * 4 + 1872;            // 121872
  const int SMALL_LDS  = 1872;

  hipError_t e = hipFuncSetAttribute(
      reinterpret_cast<const void*>(&jv_kernel<true>),
      hipFuncAttributeMaxDynamicSharedMemorySize, STAGED_LDS);
  if (e == hipSuccess) {
    jv_kernel<true><<<Bb, 256, STAGED_LDS, stream>>>(
        attribute, bbox, num_objects, cat_preds, attribute_preds, box_preds,
        gcost, gcls, partials, diag);
  } else {
    jv_kernel<false><<<Bb, 256, SMALL_LDS, stream>>>(
        attribute, bbox, num_objects, cat_preds, attribute_preds, box_preds,
        gcost, gcls, partials, (float*)nullptr);
  }

  combine_kernel<<<1, 64, 0, stream>>>(partials, num_objects, out);
}